// Round 5
// baseline (930.082 us; speedup 1.0000x reference)
//
#include <hip/hip_runtime.h>
#include <hip/hip_bf16.h>
#include <stdint.h>

#define DIMN 2048
#define KVD  512
#define NH   32
#define BATCH 2
#define SEQ  2048
#define ROWS (BATCH*SEQ)   // 4096
#define NT   (SEQ/64)      // 32 k/q tiles of 64

typedef __attribute__((ext_vector_type(4))) float f32x4;
typedef __attribute__((ext_vector_type(8))) short bf16x8;

__device__ __forceinline__ float bf2f(short s){
  union{uint32_t u;float f;} v; v.u=((uint32_t)(uint16_t)s)<<16; return v.f;
}
__device__ __forceinline__ short f2bf(float f){
  union{float f;uint32_t u;} v; v.f=f;
  uint32_t r=(v.u + 0x7fffu + ((v.u>>16)&1u))>>16; return (short)r;
}
__device__ __forceinline__ f32x4 mfma16(bf16x8 a, bf16x8 b, f32x4 c){
  return __builtin_amdgcn_mfma_f32_16x16x32_bf16(a,b,c,0,0,0);
}
__device__ __forceinline__ short ternbf(float v, float thr){
  return v > thr ? (short)0x3F80 : (v < -thr ? (short)0xBF80 : (short)0);
}

// ---------------- abs-mean reduction (deterministic, two stage, fused 4 weights) --------
__global__ void k_abssum4(const float* __restrict__ w0, const float* __restrict__ w1,
                          const float* __restrict__ w2, const float* __restrict__ w3,
                          float* __restrict__ partial){
  __shared__ float red[256];
  const float* ptrs[4] = {w0, w1, w2, w3};
  const int ns[4] = {DIMN*DIMN, KVD*DIMN, KVD*DIMN, DIMN*DIMN};
  const int wi = blockIdx.y;
  const float* w = ptrs[wi];
  const int n = ns[wi];
  float s = 0.f;
  for (int i = blockIdx.x*256 + threadIdx.x; i < n; i += 256*gridDim.x) s += fabsf(w[i]);
  red[threadIdx.x] = s; __syncthreads();
  for (int o = 128; o > 0; o >>= 1){
    if (threadIdx.x < o) red[threadIdx.x] += red[threadIdx.x+o];
    __syncthreads();
  }
  if (threadIdx.x == 0) partial[wi*256 + blockIdx.x] = red[0];
}

__global__ void k_scales(const float* __restrict__ partial, float* __restrict__ scales){
  __shared__ float red[256];
  int t = threadIdx.x;
  const int counts[4] = {DIMN*DIMN, KVD*DIMN, KVD*DIMN, DIMN*DIMN};
  for (int wi = 0; wi < 4; wi++){
    red[t] = partial[wi*256 + t]; __syncthreads();
    for (int o = 128; o > 0; o >>= 1){
      if (t < o) red[t] += red[t+o];
      __syncthreads();
    }
    if (t == 0){
      float mean = red[0] / (float)counts[wi];
      scales[wi] = 0.05f * fmaxf(mean, 1e-6f);
    }
    __syncthreads();
  }
}

// ---------------- pre-pass: x -> hi/lo bf16 ----------------
__global__ void k_prep_x(const float* __restrict__ x, short* __restrict__ hi,
                         short* __restrict__ lo){
  long i = ((long)blockIdx.x*256 + threadIdx.x)*8;
  f32x4 a = *(const f32x4*)(x+i);
  f32x4 b = *(const f32x4*)(x+i+4);
  bf16x8 h, l;
  #pragma unroll
  for (int j = 0; j < 4; j++){
    short p = f2bf(a[j]); h[j]   = p; l[j]   = f2bf(a[j]-bf2f(p));
    short q = f2bf(b[j]); h[4+j] = q; l[4+j] = f2bf(b[j]-bf2f(q));
  }
  *(bf16x8*)(hi+i) = h;
  *(bf16x8*)(lo+i) = l;
}

// ---------------- pre-pass: ternarize all 4 weights -> bf16 ----------------
__global__ void k_tern4(const float* __restrict__ w0, const float* __restrict__ w1,
                        const float* __restrict__ w2, const float* __restrict__ w3,
                        short* __restrict__ o0, short* __restrict__ o1,
                        short* __restrict__ o2, short* __restrict__ o3,
                        const float* __restrict__ scales){
  const float* ws[4] = {w0, w1, w2, w3};
  short* os[4] = {o0, o1, o2, o3};
  const int ns[4] = {DIMN*DIMN, KVD*DIMN, KVD*DIMN, DIMN*DIMN};
  const int wi = blockIdx.y;
  long i = ((long)blockIdx.x*256 + threadIdx.x)*8;
  if (i >= ns[wi]) return;
  const float thr = scales[wi];
  const float* w = ws[wi];
  f32x4 a = *(const f32x4*)(w+i);
  f32x4 b = *(const f32x4*)(w+i+4);
  bf16x8 t;
  #pragma unroll
  for (int j = 0; j < 4; j++){
    t[j]   = ternbf(a[j], thr);
    t[4+j] = ternbf(b[j], thr);
  }
  *(bf16x8*)(os[wi]+i) = t;
}

// ---------------- fast GEMM core (bf16 inputs, BK=64, 128x128 tile) ----------------
template<int SPLIT, int OUTF32>
__device__ __forceinline__ void gemm_core(
    const short* __restrict__ Ahg, const short* __restrict__ Alg,
    const short* __restrict__ Bg,
    float* __restrict__ Of, short* __restrict__ Oh, short* __restrict__ Ol,
    bool writelo, int N, int K, int bn, int bm,
    short (*AhS)[72], short (*AlS)[72], short (*BsS)[72]){
  const int tid = threadIdx.x, lane = tid & 63, w = tid >> 6;
  const int wr = w >> 1, wc = w & 1;
  const int la = lane & 15, kg = lane >> 4;
  const int srow = tid >> 1, sc = (tid & 1) * 32;
  f32x4 acc[4][4] = {};
  for (int k0 = 0; k0 < K; k0 += 64){
    {
      const short* ap = Ahg + (long)(bm+srow)*K + k0 + sc;
      #pragma unroll
      for (int i = 0; i < 4; i++)
        *(bf16x8*)&AhS[srow][sc+i*8] = *(const bf16x8*)(ap + i*8);
    }
    if constexpr (SPLIT){
      const short* alp = Alg + (long)(bm+srow)*K + k0 + sc;
      #pragma unroll
      for (int i = 0; i < 4; i++)
        *(bf16x8*)&AlS[srow][sc+i*8] = *(const bf16x8*)(alp + i*8);
    }
    {
      const short* bp = Bg + (long)(bn+srow)*K + k0 + sc;
      #pragma unroll
      for (int i = 0; i < 4; i++)
        *(bf16x8*)&BsS[srow][sc+i*8] = *(const bf16x8*)(bp + i*8);
    }
    __syncthreads();
    #pragma unroll
    for (int ks = 0; ks < 2; ks++){
      bf16x8 af[4], bfr[4];
      #pragma unroll
      for (int mi = 0; mi < 4; mi++)
        af[mi] = *(bf16x8*)&AhS[wr*64 + mi*16 + la][ks*32 + kg*8];
      #pragma unroll
      for (int ni = 0; ni < 4; ni++)
        bfr[ni] = *(bf16x8*)&BsS[wc*64 + ni*16 + la][ks*32 + kg*8];
      #pragma unroll
      for (int mi = 0; mi < 4; mi++)
        #pragma unroll
        for (int ni = 0; ni < 4; ni++)
          acc[mi][ni] = mfma16(af[mi], bfr[ni], acc[mi][ni]);
      if constexpr (SPLIT){
        bf16x8 alf[4];
        #pragma unroll
        for (int mi = 0; mi < 4; mi++)
          alf[mi] = *(bf16x8*)&AlS[wr*64 + mi*16 + la][ks*32 + kg*8];
        #pragma unroll
        for (int mi = 0; mi < 4; mi++)
          #pragma unroll
          for (int ni = 0; ni < 4; ni++)
            acc[mi][ni] = mfma16(alf[mi], bfr[ni], acc[mi][ni]);
      }
    }
    __syncthreads();
  }
  #pragma unroll
  for (int mi = 0; mi < 4; mi++)
    #pragma unroll
    for (int ni = 0; ni < 4; ni++)
      #pragma unroll
      for (int rr = 0; rr < 4; rr++){
        long row = bm + wr*64 + mi*16 + kg*4 + rr;
        long col = bn + wc*64 + ni*16 + la;
        float v = acc[mi][ni][rr];
        if constexpr (OUTF32){
          Of[row*(long)N + col] = v;
        } else {
          short hb = f2bf(v);
          Oh[row*(long)N + col] = hb;
          if (writelo)
            Ol[row*(long)N + col] = f2bf(v - bf2f(hb));
        }
      }
}

__global__ __launch_bounds__(256) void k_gemm_q(
    const short* __restrict__ Ahg, const short* __restrict__ Alg,
    const short* __restrict__ Bg, short* __restrict__ Oh, short* __restrict__ Ol,
    int N, int K){
  __shared__ short AhS[128][72];
  __shared__ short AlS[128][72];
  __shared__ short BsS[128][72];
  gemm_core<1,0>(Ahg, Alg, Bg, nullptr, Oh, Ol, true, N, K,
                 blockIdx.x*128, blockIdx.y*128, AhS, AlS, BsS);
}

// K and V GEMMs in one launch: z=0 -> K (hi+lo out), z=1 -> V (hi out)
__global__ __launch_bounds__(256) void k_gemm_kv(
    const short* __restrict__ Ahg, const short* __restrict__ Alg,
    const short* __restrict__ Bk, const short* __restrict__ Bv,
    short* __restrict__ KOh, short* __restrict__ KOl, short* __restrict__ VOh,
    int N, int K){
  __shared__ short AhS[128][72];
  __shared__ short AlS[128][72];
  __shared__ short BsS[128][72];
  const bool isK = (blockIdx.z == 0);
  gemm_core<1,0>(Ahg, Alg, isK ? Bk : Bv, nullptr,
                 isK ? KOh : VOh, isK ? KOl : nullptr, isK,
                 N, K, blockIdx.x*128, blockIdx.y*128, AhS, AlS, BsS);
}

__global__ __launch_bounds__(256) void k_gemm_o(
    const short* __restrict__ Ahg, const short* __restrict__ Bg,
    float* __restrict__ Of, int N, int K){
  __shared__ short AhS[128][72];
  __shared__ short BsS[128][72];
  gemm_core<0,1>(Ahg, nullptr, Bg, Of, nullptr, nullptr, false, N, K,
                 blockIdx.x*128, blockIdx.y*128, AhS, nullptr, BsS);
}

// ---------------- fallback GEMMs (fused f32 staging, round-4 proven) ----------------
template<int WRITELO>
__global__ __launch_bounds__(256) void k_gemm_qkv_fb(
    const float* __restrict__ X, const float* __restrict__ W,
    const float* __restrict__ scales, int wi,
    short* __restrict__ Oh, short* __restrict__ Ol,
    int M, int N, int K){
  __shared__ short Ah[128][40];
  __shared__ short Al[128][40];
  __shared__ short Bs[128][40];
  const float thr = scales[wi];
  const int bn = blockIdx.x*128, bm = blockIdx.y*128;
  const int tid = threadIdx.x, lane = tid & 63, w = tid >> 6;
  const int wr = w >> 1, wc = w & 1;
  const int la = lane & 15, kg = lane >> 4;
  const int srow = tid >> 1, sc = (tid & 1) * 16;
  f32x4 acc[4][4] = {};
  for (int k0 = 0; k0 < K; k0 += 32){
    {
      const float* xs = X + (long)(bm+srow)*K + k0 + sc;
      f32x4 xv0 = *(const f32x4*)xs;
      f32x4 xv1 = *(const f32x4*)(xs+4);
      f32x4 xv2 = *(const f32x4*)(xs+8);
      f32x4 xv3 = *(const f32x4*)(xs+12);
      bf16x8 h0, l0, h1, l1;
      #pragma unroll
      for (int i = 0; i < 4; i++){
        short a = f2bf(xv0[i]); h0[i]   = a; l0[i]   = f2bf(xv0[i]-bf2f(a));
        short b = f2bf(xv1[i]); h0[4+i] = b; l0[4+i] = f2bf(xv1[i]-bf2f(b));
        short c = f2bf(xv2[i]); h1[i]   = c; l1[i]   = f2bf(xv2[i]-bf2f(c));
        short d = f2bf(xv3[i]); h1[4+i] = d; l1[4+i] = f2bf(xv3[i]-bf2f(d));
      }
      *(bf16x8*)&Ah[srow][sc]   = h0;  *(bf16x8*)&Ah[srow][sc+8] = h1;
      *(bf16x8*)&Al[srow][sc]   = l0;  *(bf16x8*)&Al[srow][sc+8] = l1;
    }
    {
      const float* wsrc = W + (long)(bn+srow)*K + k0 + sc;
      f32x4 wv0 = *(const f32x4*)wsrc;
      f32x4 wv1 = *(const f32x4*)(wsrc+4);
      f32x4 wv2 = *(const f32x4*)(wsrc+8);
      f32x4 wv3 = *(const f32x4*)(wsrc+12);
      bf16x8 t0, t1;
      #pragma unroll
      for (int i = 0; i < 4; i++){
        t0[i]   = ternbf(wv0[i], thr);
        t0[4+i] = ternbf(wv1[i], thr);
        t1[i]   = ternbf(wv2[i], thr);
        t1[4+i] = ternbf(wv3[i], thr);
      }
      *(bf16x8*)&Bs[srow][sc]   = t0;  *(bf16x8*)&Bs[srow][sc+8] = t1;
    }
    __syncthreads();
    bf16x8 af[4], alf[4], bfr[4];
    #pragma unroll
    for (int mi = 0; mi < 4; mi++){
      af[mi]  = *(bf16x8*)&Ah[wr*64 + mi*16 + la][kg*8];
      alf[mi] = *(bf16x8*)&Al[wr*64 + mi*16 + la][kg*8];
    }
    #pragma unroll
    for (int ni = 0; ni < 4; ni++)
      bfr[ni] = *(bf16x8*)&Bs[wc*64 + ni*16 + la][kg*8];
    #pragma unroll
    for (int mi = 0; mi < 4; mi++)
      #pragma unroll
      for (int ni = 0; ni < 4; ni++){
        acc[mi][ni] = mfma16(af[mi],  bfr[ni], acc[mi][ni]);
        acc[mi][ni] = mfma16(alf[mi], bfr[ni], acc[mi][ni]);
      }
    __syncthreads();
  }
  #pragma unroll
  for (int mi = 0; mi < 4; mi++)
    #pragma unroll
    for (int ni = 0; ni < 4; ni++)
      #pragma unroll
      for (int rr = 0; rr < 4; rr++){
        long row = bm + wr*64 + mi*16 + kg*4 + rr;
        long col = bn + wc*64 + ni*16 + la;
        float v = acc[mi][ni][rr];
        short hb = f2bf(v);
        Oh[row*(long)N + col] = hb;
        if constexpr (WRITELO)
          Ol[row*(long)N + col] = f2bf(v - bf2f(hb));
      }
}

__global__ __launch_bounds__(256) void k_gemm_out_fb(
    const short* __restrict__ A, const float* __restrict__ W,
    const float* __restrict__ scales, int wi,
    float* __restrict__ Of, int M, int N, int K){
  __shared__ short As[128][40];
  __shared__ short Bs[128][40];
  const float thr = scales[wi];
  const int bn = blockIdx.x*128, bm = blockIdx.y*128;
  const int tid = threadIdx.x, lane = tid & 63, w = tid >> 6;
  const int wr = w >> 1, wc = w & 1;
  const int la = lane & 15, kg = lane >> 4;
  const int srow = tid >> 1, sc = (tid & 1) * 16;
  f32x4 acc[4][4] = {};
  for (int k0 = 0; k0 < K; k0 += 32){
    *(bf16x8*)&As[srow][sc]   = *(const bf16x8*)(A + (long)(bm+srow)*K + k0 + sc);
    *(bf16x8*)&As[srow][sc+8] = *(const bf16x8*)(A + (long)(bm+srow)*K + k0 + sc + 8);
    {
      const float* wsrc = W + (long)(bn+srow)*K + k0 + sc;
      f32x4 wv0 = *(const f32x4*)wsrc;
      f32x4 wv1 = *(const f32x4*)(wsrc+4);
      f32x4 wv2 = *(const f32x4*)(wsrc+8);
      f32x4 wv3 = *(const f32x4*)(wsrc+12);
      bf16x8 t0, t1;
      #pragma unroll
      for (int i = 0; i < 4; i++){
        t0[i]   = ternbf(wv0[i], thr);
        t0[4+i] = ternbf(wv1[i], thr);
        t1[i]   = ternbf(wv2[i], thr);
        t1[4+i] = ternbf(wv3[i], thr);
      }
      *(bf16x8*)&Bs[srow][sc]   = t0;  *(bf16x8*)&Bs[srow][sc+8] = t1;
    }
    __syncthreads();
    bf16x8 af[4], bfr[4];
    #pragma unroll
    for (int mi = 0; mi < 4; mi++)
      af[mi] = *(bf16x8*)&As[wr*64 + mi*16 + la][kg*8];
    #pragma unroll
    for (int ni = 0; ni < 4; ni++)
      bfr[ni] = *(bf16x8*)&Bs[wc*64 + ni*16 + la][kg*8];
    #pragma unroll
    for (int mi = 0; mi < 4; mi++)
      #pragma unroll
      for (int ni = 0; ni < 4; ni++)
        acc[mi][ni] = mfma16(af[mi], bfr[ni], acc[mi][ni]);
    __syncthreads();
  }
  #pragma unroll
  for (int mi = 0; mi < 4; mi++)
    #pragma unroll
    for (int ni = 0; ni < 4; ni++)
      #pragma unroll
      for (int rr = 0; rr < 4; rr++){
        long row = bm + wr*64 + mi*16 + kg*4 + rr;
        long col = bn + wc*64 + ni*16 + la;
        Of[row*(long)N + col] = acc[mi][ni][rr];
      }
}

// ---------------- GQA causal flash attention (LPT scheduling, K-prefetch) ----------------
// grid: (NT=32, head=32, batch=2). qt = NT-1-bx so heaviest blocks dispatch first.
// Scores use 3-MFMA split (qhi*khi + qhi*klo + qlo*khi) for fp32-class accuracy.
__global__ __launch_bounds__(256) void k_attn(
    const short* __restrict__ qhi, const short* __restrict__ qlo,
    const short* __restrict__ khi, const short* __restrict__ klo,
    const short* __restrict__ vhi, short* __restrict__ attout){
  __shared__ short Vt[64][72];   // V transposed: Vt[d][kv]
  __shared__ short P[64][72];    // probs tile
  const int qt = NT - 1 - blockIdx.x, h = blockIdx.y, b = blockIdx.z;
  const int g = h >> 2;
  const int tid = threadIdx.x, w = tid >> 6, lane = tid & 63;
  const int la = lane & 15, kg = lane >> 4;
  const int qbase = qt*64;

  bf16x8 qh[2], ql[2];
  {
    long qrow = (long)(b*SEQ + qbase + w*16 + la);
    #pragma unroll
    for (int ks = 0; ks < 2; ks++){
      long off = qrow*DIMN + h*64 + ks*32 + kg*8;
      qh[ks] = *(const bf16x8*)(qhi + off);
      ql[ks] = *(const bf16x8*)(qlo + off);
    }
  }
  f32x4 Oacc[4] = {};
  float m[4], l[4];
  #pragma unroll
  for (int r = 0; r < 4; r++){ m[r] = -INFINITY; l[r] = 0.f; }

  for (int kt = 0; kt <= qt; kt++){
    // prefetch K-hi fragments (latency hides under V staging + barriers)
    bf16x8 kfh[4][2];
    #pragma unroll
    for (int ni = 0; ni < 4; ni++)
      #pragma unroll
      for (int ks = 0; ks < 2; ks++)
        kfh[ni][ks] = *(const bf16x8*)(khi +
            (long)(b*SEQ + kt*64 + ni*16 + la)*KVD + g*64 + ks*32 + kg*8);

    __syncthreads();
    // stage V transposed
    {
      int kk = tid >> 2, dg = tid & 3;
      long vrow = (long)(b*SEQ + kt*64 + kk)*KVD + g*64 + dg*16;
      bf16x8 v0 = *(const bf16x8*)(vhi + vrow);
      bf16x8 v1 = *(const bf16x8*)(vhi + vrow + 8);
      #pragma unroll
      for (int i = 0; i < 8; i++){
        Vt[dg*16 + i][kk]     = v0[i];
        Vt[dg*16 + 8 + i][kk] = v1[i];
      }
    }
    __syncthreads();

    // scores
    f32x4 s[4];
    #pragma unroll
    for (int ni = 0; ni < 4; ni++){
      f32x4 a = {0.f,0.f,0.f,0.f};
      #pragma unroll
      for (int ks = 0; ks < 2; ks++){
        bf16x8 kl = *(const bf16x8*)(klo +
            (long)(b*SEQ + kt*64 + ni*16 + la)*KVD + g*64 + ks*32 + kg*8);
        a = mfma16(qh[ks], kfh[ni][ks], a);
        a = mfma16(ql[ks], kfh[ni][ks], a);
        a = mfma16(qh[ks], kl, a);
      }
      s[ni] = a;
    }

    const bool lastTile = (kt == qt);
    #pragma unroll
    for (int ni = 0; ni < 4; ni++)
      #pragma unroll
      for (int r = 0; r < 4; r++){
        float v = s[ni][r] * 0.125f;
        if (lastTile){
          int kc = kt*64 + ni*16 + la;
          int qr = qbase + w*16 + kg*4 + r;
          if (kc > qr) v = -INFINITY;
        }
        s[ni][r] = v;
      }

    // online softmax
    float ef[4];
    #pragma unroll
    for (int r = 0; r < 4; r++){
      float v = fmaxf(fmaxf(s[0][r], s[1][r]), fmaxf(s[2][r], s[3][r]));
      for (int o = 1; o < 16; o <<= 1) v = fmaxf(v, __shfl_xor(v, o, 64));
      float mn = fmaxf(m[r], v);
      ef[r] = __expf(m[r] - mn);
      m[r] = mn;
    }
    #pragma unroll
    for (int r = 0; r < 4; r++){
      float rs = 0.f;
      #pragma unroll
      for (int ni = 0; ni < 4; ni++){
        float p = __expf(s[ni][r] - m[r]);
        s[ni][r] = p;
        rs += p;
      }
      for (int o = 1; o < 16; o <<= 1) rs += __shfl_xor(rs, o, 64);
      l[r] = l[r]*ef[r] + rs;
    }
    #pragma unroll
    for (int d = 0; d < 4; d++)
      #pragma unroll
      for (int r = 0; r < 4; r++) Oacc[d][r] *= ef[r];

    // P -> LDS bf16, read back as A-fragments
    #pragma unroll
    for (int ni = 0; ni < 4; ni++)
      #pragma unroll
      for (int r = 0; r < 4; r++)
        P[w*16 + kg*4 + r][ni*16 + la] = f2bf(s[ni][r]);
    #pragma unroll
    for (int ks = 0; ks < 2; ks++){
      bf16x8 pa = *(bf16x8*)&P[w*16 + la][ks*32 + kg*8];
      #pragma unroll
      for (int d = 0; d < 4; d++){
        bf16x8 vb = *(bf16x8*)&Vt[d*16 + la][ks*32 + kg*8];
        Oacc[d] = mfma16(pa, vb, Oacc[d]);
      }
    }
  }

  // finalize
  #pragma unroll
  for (int d = 0; d < 4; d++)
    #pragma unroll
    for (int r = 0; r < 4; r++){
      float v = Oacc[d][r] / l[r];
      long row = (long)(b*SEQ + qbase + w*16 + kg*4 + r);
      attout[row*DIMN + h*64 + d*16 + la] = f2bf(v);
    }
}

// ---------------- host ----------------
extern "C" void kernel_launch(void* const* d_in, const int* in_sizes, int n_in,
                              void* d_out, int out_size, void* d_ws, size_t ws_size,
                              hipStream_t stream){
  const float* x  = (const float*)d_in[0];
  const float* wq = (const float*)d_in[1];
  const float* wk = (const float*)d_in[2];
  const float* wv = (const float*)d_in[3];
  const float* wo = (const float*)d_in[4];
  float* out = (float*)d_out;
  char* ws = (char*)d_ws;

  const size_t SZ_QD = (size_t)ROWS*DIMN*2;   // 16 MB
  const size_t SZ_KD = (size_t)ROWS*KVD*2;    // 4 MB
  const size_t SZ_WQ = (size_t)DIMN*DIMN*2;   // 8 MB
  const size_t SZ_WK = (size_t)KVD*DIMN*2;    // 2 MB

  float* scales   = (float*)ws;
  float* partials = (float*)(ws + 1024);
  size_t off = 65536;
  auto alloc = [&](size_t bytes)->char*{
    char* p = ws + off; off += (bytes + 255) & ~(size_t)255; return p;
  };

  // shared pre-work: thresholds
  {
    dim3 g(256, 4);
    k_abssum4<<<g,256,0,stream>>>(wq, wk, wv, wo, partials);
  }
  k_scales<<<1,256,0,stream>>>(partials, scales);

  // fast path: pre-converted bf16 operands (needs ~96 MB)
  const size_t NEED_FAST = 65536 + 2*SZ_QD /*xhi,xlo*/ + 2*SZ_WQ + 2*SZ_WK /*w_t*/
                         + 2*SZ_QD /*qhi,qlo*/ + 3*SZ_KD /*khi,klo,vhi*/;
  const size_t NEED_FB   = 65536 + 3*SZ_QD + 3*SZ_KD;

  if (ws_size >= NEED_FAST){
    short* xhi = (short*)alloc(SZ_QD);
    short* xlo = (short*)alloc(SZ_QD);
    short* wqT = (short*)alloc(SZ_WQ);
    short* wkT = (short*)alloc(SZ_WK);
    short* wvT = (short*)alloc(SZ_WK);
    short* woT = (short*)alloc(SZ_WQ);
    short* qhib = (short*)alloc(SZ_QD);
    short* qlob = (short*)alloc(SZ_QD);
    short* khib = (short*)alloc(SZ_KD);
    short* klob = (short*)alloc(SZ_KD);
    short* vhib = (short*)alloc(SZ_KD);
    short* atto = xhi;   // alias: xhi dead after V GEMM

    {
      dim3 g(2048, 4);
      k_tern4<<<g,256,0,stream>>>(wq, wk, wv, wo, wqT, wkT, wvT, woT, scales);
    }
    k_prep_x<<<4096,256,0,stream>>>(x, xhi, xlo);

    {
      dim3 g(DIMN/128, ROWS/128);
      k_gemm_q<<<g,256,0,stream>>>(xhi, xlo, wqT, qhib, qlob, DIMN, DIMN);
    }
    {
      dim3 g(KVD/128, ROWS/128, 2);
      k_gemm_kv<<<g,256,0,stream>>>(xhi, xlo, wkT, wvT, khib, klob, vhib, KVD, DIMN);
    }
    {
      dim3 g(NT, NH, BATCH);
      k_attn<<<g,256,0,stream>>>(qhib, qlob, khib, klob, vhib, atto);
    }
    {
      dim3 g(DIMN/128, ROWS/128);
      k_gemm_o<<<g,256,0,stream>>>(atto, woT, out, DIMN, DIMN);
    }
  } else if (ws_size >= NEED_FB){
    short* qhib = (short*)alloc(SZ_QD);
    short* qlob = (short*)alloc(SZ_QD);
    short* khib = (short*)alloc(SZ_KD);
    short* klob = (short*)alloc(SZ_KD);
    short* vhib = (short*)alloc(SZ_KD);
    short* atto = (short*)alloc(SZ_QD);

    {
      dim3 g(DIMN/128, ROWS/128);
      k_gemm_qkv_fb<1><<<g,256,0,stream>>>(x, wq, scales, 0, qhib, qlob, ROWS, DIMN, DIMN);
    }
    {
      dim3 g(KVD/128, ROWS/128);
      k_gemm_qkv_fb<1><<<g,256,0,stream>>>(x, wk, scales, 1, khib, klob, ROWS, KVD, DIMN);
      k_gemm_qkv_fb<0><<<g,256,0,stream>>>(x, wv, scales, 2, vhib, nullptr, ROWS, KVD, DIMN);
    }
    {
      dim3 g(NT, NH, BATCH);
      k_attn<<<g,256,0,stream>>>(qhib, qlob, khib, klob, vhib, atto);
    }
    {
      dim3 g(DIMN/128, ROWS/128);
      k_gemm_out_fb<<<g,256,0,stream>>>(atto, wo, scales, 3, out, ROWS, DIMN, DIMN);
    }
  }
}

// Round 6
// 688.410 us; speedup vs baseline: 1.3511x; 1.3511x over previous
//
#include <hip/hip_runtime.h>
#include <hip/hip_bf16.h>
#include <stdint.h>

#define DIMN 2048
#define KVD  512
#define NH   32
#define BATCH 2
#define SEQ  2048
#define ROWS (BATCH*SEQ)   // 4096
#define NT   (SEQ/64)      // 32 k/q tiles of 64

typedef __attribute__((ext_vector_type(4))) float f32x4;
typedef __attribute__((ext_vector_type(8))) short bf16x8;

__device__ __forceinline__ float bf2f(short s){
  union{uint32_t u;float f;} v; v.u=((uint32_t)(uint16_t)s)<<16; return v.f;
}
__device__ __forceinline__ short f2bf(float f){
  union{float f;uint32_t u;} v; v.f=f;
  uint32_t r=(v.u + 0x7fffu + ((v.u>>16)&1u))>>16; return (short)r;
}
__device__ __forceinline__ f32x4 mfma16(bf16x8 a, bf16x8 b, f32x4 c){
  return __builtin_amdgcn_mfma_f32_16x16x32_bf16(a,b,c,0,0,0);
}
__device__ __forceinline__ short ternbf(float v, float thr){
  return v > thr ? (short)0x3F80 : (v < -thr ? (short)0xBF80 : (short)0);
}

// ---------------- abs-mean reduction (deterministic, two stage) ----------------
__global__ void k_abssum4(const float* __restrict__ w0, const float* __restrict__ w1,
                          const float* __restrict__ w2, const float* __restrict__ w3,
                          float* __restrict__ partial){
  __shared__ float red[256];
  const float* ptrs[4] = {w0, w1, w2, w3};
  const int ns[4] = {DIMN*DIMN, KVD*DIMN, KVD*DIMN, DIMN*DIMN};
  const int wi = blockIdx.y;
  const float* w = ptrs[wi];
  const int n = ns[wi];
  float s = 0.f;
  for (int i = blockIdx.x*256 + threadIdx.x; i < n; i += 256*gridDim.x) s += fabsf(w[i]);
  red[threadIdx.x] = s; __syncthreads();
  for (int o = 128; o > 0; o >>= 1){
    if (threadIdx.x < o) red[threadIdx.x] += red[threadIdx.x+o];
    __syncthreads();
  }
  if (threadIdx.x == 0) partial[wi*256 + blockIdx.x] = red[0];
}

__global__ void k_scales(const float* __restrict__ partial, float* __restrict__ scales){
  __shared__ float red[256];
  int t = threadIdx.x;
  const int counts[4] = {DIMN*DIMN, KVD*DIMN, KVD*DIMN, DIMN*DIMN};
  for (int wi = 0; wi < 4; wi++){
    red[t] = partial[wi*256 + t]; __syncthreads();
    for (int o = 128; o > 0; o >>= 1){
      if (t < o) red[t] += red[t+o];
      __syncthreads();
    }
    if (t == 0){
      float mean = red[0] / (float)counts[wi];
      scales[wi] = 0.05f * fmaxf(mean, 1e-6f);
    }
    __syncthreads();
  }
}

// ---------------- pre-pass: x -> hi/lo bf16 ----------------
__global__ void k_prep_x(const float* __restrict__ x, short* __restrict__ hi,
                         short* __restrict__ lo){
  long i = ((long)blockIdx.x*256 + threadIdx.x)*8;
  f32x4 a = *(const f32x4*)(x+i);
  f32x4 b = *(const f32x4*)(x+i+4);
  bf16x8 h, l;
  #pragma unroll
  for (int j = 0; j < 4; j++){
    short p = f2bf(a[j]); h[j]   = p; l[j]   = f2bf(a[j]-bf2f(p));
    short q = f2bf(b[j]); h[4+j] = q; l[4+j] = f2bf(b[j]-bf2f(q));
  }
  *(bf16x8*)(hi+i) = h;
  *(bf16x8*)(lo+i) = l;
}

// ---------------- pre-pass: ternarize all 4 weights -> bf16 ----------------
__global__ void k_tern4(const float* __restrict__ w0, const float* __restrict__ w1,
                        const float* __restrict__ w2, const float* __restrict__ w3,
                        short* __restrict__ o0, short* __restrict__ o1,
                        short* __restrict__ o2, short* __restrict__ o3,
                        const float* __restrict__ scales){
  const float* ws[4] = {w0, w1, w2, w3};
  short* os[4] = {o0, o1, o2, o3};
  const int ns[4] = {DIMN*DIMN, KVD*DIMN, KVD*DIMN, DIMN*DIMN};
  const int wi = blockIdx.y;
  long i = ((long)blockIdx.x*256 + threadIdx.x)*8;
  if (i >= ns[wi]) return;
  const float thr = scales[wi];
  const float* w = ws[wi];
  f32x4 a = *(const f32x4*)(w+i);
  f32x4 b = *(const f32x4*)(w+i+4);
  bf16x8 t;
  #pragma unroll
  for (int j = 0; j < 4; j++){
    t[j]   = ternbf(a[j], thr);
    t[4+j] = ternbf(b[j], thr);
  }
  *(bf16x8*)(os[wi]+i) = t;
}

// ---------------- GEMM core (bf16 inputs, BK=64, 128x128 tile) ----------------
// SPLITA: A has hi+lo parts.  SPLITB: B has hi+lo parts.  OUTF32: f32 output.
template<int SPLITA, int SPLITB, int OUTF32>
__device__ __forceinline__ void gemm_core(
    const short* __restrict__ Ahg, const short* __restrict__ Alg,
    const short* __restrict__ Bg,  const short* __restrict__ Blg,
    float* __restrict__ Of, short* __restrict__ Oh, short* __restrict__ Ol,
    bool writelo, int N, int K, int bn, int bm,
    short (*AhS)[72], short (*AlS)[72], short (*BsS)[72], short (*BlS)[72]){
  const int tid = threadIdx.x, lane = tid & 63, w = tid >> 6;
  const int wr = w >> 1, wc = w & 1;
  const int la = lane & 15, kg = lane >> 4;
  const int srow = tid >> 1, sc = (tid & 1) * 32;
  f32x4 acc[4][4] = {};
  for (int k0 = 0; k0 < K; k0 += 64){
    {
      const short* ap = Ahg + (long)(bm+srow)*K + k0 + sc;
      #pragma unroll
      for (int i = 0; i < 4; i++)
        *(bf16x8*)&AhS[srow][sc+i*8] = *(const bf16x8*)(ap + i*8);
    }
    if constexpr (SPLITA){
      const short* alp = Alg + (long)(bm+srow)*K + k0 + sc;
      #pragma unroll
      for (int i = 0; i < 4; i++)
        *(bf16x8*)&AlS[srow][sc+i*8] = *(const bf16x8*)(alp + i*8);
    }
    {
      const short* bp = Bg + (long)(bn+srow)*K + k0 + sc;
      #pragma unroll
      for (int i = 0; i < 4; i++)
        *(bf16x8*)&BsS[srow][sc+i*8] = *(const bf16x8*)(bp + i*8);
    }
    if constexpr (SPLITB){
      const short* blp = Blg + (long)(bn+srow)*K + k0 + sc;
      #pragma unroll
      for (int i = 0; i < 4; i++)
        *(bf16x8*)&BlS[srow][sc+i*8] = *(const bf16x8*)(blp + i*8);
    }
    __syncthreads();
    #pragma unroll
    for (int ks = 0; ks < 2; ks++){
      bf16x8 af[4], bfr[4];
      #pragma unroll
      for (int mi = 0; mi < 4; mi++)
        af[mi] = *(bf16x8*)&AhS[wr*64 + mi*16 + la][ks*32 + kg*8];
      #pragma unroll
      for (int ni = 0; ni < 4; ni++)
        bfr[ni] = *(bf16x8*)&BsS[wc*64 + ni*16 + la][ks*32 + kg*8];
      #pragma unroll
      for (int mi = 0; mi < 4; mi++)
        #pragma unroll
        for (int ni = 0; ni < 4; ni++)
          acc[mi][ni] = mfma16(af[mi], bfr[ni], acc[mi][ni]);
      if constexpr (SPLITA){
        bf16x8 alf[4];
        #pragma unroll
        for (int mi = 0; mi < 4; mi++)
          alf[mi] = *(bf16x8*)&AlS[wr*64 + mi*16 + la][ks*32 + kg*8];
        #pragma unroll
        for (int mi = 0; mi < 4; mi++)
          #pragma unroll
          for (int ni = 0; ni < 4; ni++)
            acc[mi][ni] = mfma16(alf[mi], bfr[ni], acc[mi][ni]);
      }
      if constexpr (SPLITB){
        bf16x8 blf[4];
        #pragma unroll
        for (int ni = 0; ni < 4; ni++)
          blf[ni] = *(bf16x8*)&BlS[wc*64 + ni*16 + la][ks*32 + kg*8];
        #pragma unroll
        for (int mi = 0; mi < 4; mi++)
          #pragma unroll
          for (int ni = 0; ni < 4; ni++)
            acc[mi][ni] = mfma16(af[mi], blf[ni], acc[mi][ni]);
      }
    }
    __syncthreads();
  }
  #pragma unroll
  for (int mi = 0; mi < 4; mi++)
    #pragma unroll
    for (int ni = 0; ni < 4; ni++)
      #pragma unroll
      for (int rr = 0; rr < 4; rr++){
        long row = bm + wr*64 + mi*16 + kg*4 + rr;
        long col = bn + wc*64 + ni*16 + la;
        float v = acc[mi][ni][rr];
        if constexpr (OUTF32){
          Of[row*(long)N + col] = v;
        } else {
          short hb = f2bf(v);
          Oh[row*(long)N + col] = hb;
          if (writelo)
            Ol[row*(long)N + col] = f2bf(v - bf2f(hb));
        }
      }
}

__global__ __launch_bounds__(256) void k_gemm_q(
    const short* __restrict__ Ahg, const short* __restrict__ Alg,
    const short* __restrict__ Bg, short* __restrict__ Oh, short* __restrict__ Ol,
    int N, int K){
  __shared__ short S0[128][72];
  __shared__ short S1[128][72];
  __shared__ short S2[128][72];
  gemm_core<1,0,0>(Ahg, Alg, Bg, nullptr, nullptr, Oh, Ol, true, N, K,
                   blockIdx.x*128, blockIdx.y*128, S0, S1, S2, nullptr);
}

// z=0: K GEMM  khi/klo[token][d] = (xhi+xlo) wkT^T   (grid 4 x 32)
// z=1: V^T GEMM  vT[d][token] = wvT (xhi+xlo)^T      (grid 4 x 32, roles swapped)
__global__ __launch_bounds__(256) void k_gemm_kvt(
    const short* __restrict__ xhi, const short* __restrict__ xlo,
    const short* __restrict__ wkT, const short* __restrict__ wvT,
    short* __restrict__ KOh, short* __restrict__ KOl, short* __restrict__ VT,
    int K){
  __shared__ short S0[128][72];
  __shared__ short S1[128][72];
  __shared__ short S2[128][72];
  if (blockIdx.z == 0){
    gemm_core<1,0,0>(xhi, xlo, wkT, nullptr, nullptr, KOh, KOl, true, KVD, K,
                     blockIdx.x*128, blockIdx.y*128, S0, S1, S2, nullptr);
  } else {
    gemm_core<0,1,0>(wvT, nullptr, xhi, xlo, nullptr, VT, nullptr, false, ROWS, K,
                     blockIdx.y*128, blockIdx.x*128, S0, nullptr, S1, S2);
  }
}

__global__ __launch_bounds__(256) void k_gemm_o(
    const short* __restrict__ Ahg, const short* __restrict__ Bg,
    float* __restrict__ Of, int N, int K){
  __shared__ short S0[128][72];
  __shared__ short S2[128][72];
  gemm_core<0,0,1>(Ahg, nullptr, Bg, nullptr, Of, nullptr, nullptr, false, N, K,
                   blockIdx.x*128, blockIdx.y*128, S0, nullptr, S2, nullptr);
}

// ---------------- GQA causal flash attention ----------------
// Balanced pairing: grid (NT/2=16, head=32, batch=2); block qp does q-tiles {qp, NT-1-qp}
// = exactly NT+1 = 33 k-tiles -> uniform work. 4 waves, wave w owns q rows w*16..+15.
// BARRIER-FREE: V consumed directly from V^T global buffer (B-fragment = contiguous
// 16B load); P round-trip through LDS is wave-private. Scores use 3-MFMA hi/lo split.
__global__ __launch_bounds__(256) void k_attn(
    const short* __restrict__ qhi, const short* __restrict__ qlo,
    const short* __restrict__ khi, const short* __restrict__ klo,
    const short* __restrict__ vT, short* __restrict__ attout){
  __shared__ short P[64][72];
  const int qp = blockIdx.x, h = blockIdx.y, b = blockIdx.z;
  const int g = h >> 2;
  const int tid = threadIdx.x, w = tid >> 6, lane = tid & 63;
  const int la = lane & 15, kg = lane >> 4;

  for (int phase = 0; phase < 2; phase++){
    const int qt = phase ? (NT - 1 - qp) : qp;
    const int qbase = qt*64;

    bf16x8 qh[2], ql[2];
    {
      long qrow = (long)(b*SEQ + qbase + w*16 + la);
      #pragma unroll
      for (int ks = 0; ks < 2; ks++){
        long off = qrow*DIMN + h*64 + ks*32 + kg*8;
        qh[ks] = *(const bf16x8*)(qhi + off);
        ql[ks] = *(const bf16x8*)(qlo + off);
      }
    }
    f32x4 Oacc[4] = {};
    float m[4], l[4];
    #pragma unroll
    for (int r = 0; r < 4; r++){ m[r] = -INFINITY; l[r] = 0.f; }

    for (int kt = 0; kt <= qt; kt++){
      const short* kb  = khi + (long)(b*SEQ + kt*64)*KVD + g*64;
      const short* klb = klo + (long)(b*SEQ + kt*64)*KVD + g*64;

      // scores (3-MFMA split)
      f32x4 s[4];
      #pragma unroll
      for (int ni = 0; ni < 4; ni++){
        f32x4 a = {0.f,0.f,0.f,0.f};
        #pragma unroll
        for (int ks = 0; ks < 2; ks++){
          long ko = (long)(ni*16 + la)*KVD + ks*32 + kg*8;
          bf16x8 kh = *(const bf16x8*)(kb + ko);
          bf16x8 kl = *(const bf16x8*)(klb + ko);
          a = mfma16(qh[ks], kh, a);
          a = mfma16(ql[ks], kh, a);
          a = mfma16(qh[ks], kl, a);
        }
        s[ni] = a;
      }

      const bool lastTile = (kt == qt);
      #pragma unroll
      for (int ni = 0; ni < 4; ni++)
        #pragma unroll
        for (int r = 0; r < 4; r++){
          float v = s[ni][r] * 0.125f;
          if (lastTile){
            int kc = kt*64 + ni*16 + la;
            int qr = qbase + w*16 + kg*4 + r;
            if (kc > qr) v = -INFINITY;
          }
          s[ni][r] = v;
        }

      // online softmax (16-lane row groups)
      float ef[4];
      #pragma unroll
      for (int r = 0; r < 4; r++){
        float v = fmaxf(fmaxf(s[0][r], s[1][r]), fmaxf(s[2][r], s[3][r]));
        for (int o = 1; o < 16; o <<= 1) v = fmaxf(v, __shfl_xor(v, o, 64));
        float mn = fmaxf(m[r], v);
        ef[r] = __expf(m[r] - mn);
        m[r] = mn;
      }
      #pragma unroll
      for (int r = 0; r < 4; r++){
        float rs = 0.f;
        #pragma unroll
        for (int ni = 0; ni < 4; ni++){
          float p = __expf(s[ni][r] - m[r]);
          s[ni][r] = p;
          rs += p;
        }
        for (int o = 1; o < 16; o <<= 1) rs += __shfl_xor(rs, o, 64);
        l[r] = l[r]*ef[r] + rs;
      }
      #pragma unroll
      for (int d = 0; d < 4; d++)
        #pragma unroll
        for (int r = 0; r < 4; r++) Oacc[d][r] *= ef[r];

      // P -> LDS bf16 (wave-private rows), read back as A-fragments
      #pragma unroll
      for (int ni = 0; ni < 4; ni++)
        #pragma unroll
        for (int r = 0; r < 4; r++)
          P[w*16 + kg*4 + r][ni*16 + la] = f2bf(s[ni][r]);

      const short* vtb = vT + (long)(g*64)*ROWS + b*SEQ + kt*64;
      #pragma unroll
      for (int ks = 0; ks < 2; ks++){
        bf16x8 pa = *(bf16x8*)&P[w*16 + la][ks*32 + kg*8];
        #pragma unroll
        for (int d = 0; d < 4; d++){
          bf16x8 vb = *(const bf16x8*)(vtb + (long)(d*16 + la)*ROWS + ks*32 + kg*8);
          Oacc[d] = mfma16(pa, vb, Oacc[d]);
        }
      }
    }

    // finalize
    #pragma unroll
    for (int d = 0; d < 4; d++)
      #pragma unroll
      for (int r = 0; r < 4; r++){
        float v = Oacc[d][r] / l[r];
        long row = (long)(b*SEQ + qbase + w*16 + kg*4 + r);
        attout[row*DIMN + h*64 + d*16 + la] = f2bf(v);
      }
  }
}

// ---------------- host ----------------
extern "C" void kernel_launch(void* const* d_in, const int* in_sizes, int n_in,
                              void* d_out, int out_size, void* d_ws, size_t ws_size,
                              hipStream_t stream){
  const float* x  = (const float*)d_in[0];
  const float* wq = (const float*)d_in[1];
  const float* wk = (const float*)d_in[2];
  const float* wv = (const float*)d_in[3];
  const float* wo = (const float*)d_in[4];
  float* out = (float*)d_out;
  char* ws = (char*)d_ws;

  const size_t SZ_QD = (size_t)ROWS*DIMN*2;   // 16 MB
  const size_t SZ_KD = (size_t)ROWS*KVD*2;    // 4 MB
  const size_t SZ_WQ = (size_t)DIMN*DIMN*2;   // 8 MB
  const size_t SZ_WK = (size_t)KVD*DIMN*2;    // 2 MB
  const size_t NEED = 65536 + 2*SZ_QD + 2*SZ_WQ + 2*SZ_WK + 2*SZ_QD + 3*SZ_KD;
  if (ws_size < NEED) return;

  float* scales   = (float*)ws;
  float* partials = (float*)(ws + 1024);
  size_t off = 65536;
  auto alloc = [&](size_t bytes)->char*{
    char* p = ws + off; off += (bytes + 255) & ~(size_t)255; return p;
  };
  short* xhi = (short*)alloc(SZ_QD);
  short* xlo = (short*)alloc(SZ_QD);
  short* wqT = (short*)alloc(SZ_WQ);
  short* wkT = (short*)alloc(SZ_WK);
  short* wvT = (short*)alloc(SZ_WK);
  short* woT = (short*)alloc(SZ_WQ);
  short* qhib = (short*)alloc(SZ_QD);
  short* qlob = (short*)alloc(SZ_QD);
  short* khib = (short*)alloc(SZ_KD);
  short* klob = (short*)alloc(SZ_KD);
  short* vTb  = (short*)alloc(SZ_KD);   // V^T: [KVD][ROWS]
  short* atto = xhi;                    // alias: xhi dead after KVT GEMM

  // 1) thresholds
  {
    dim3 g(256, 4);
    k_abssum4<<<g,256,0,stream>>>(wq, wk, wv, wo, partials);
  }
  k_scales<<<1,256,0,stream>>>(partials, scales);

  // 2) pre-convert operands
  {
    dim3 g(2048, 4);
    k_tern4<<<g,256,0,stream>>>(wq, wk, wv, wo, wqT, wkT, wvT, woT, scales);
  }
  k_prep_x<<<4096,256,0,stream>>>(x, xhi, xlo);

  // 3) Q GEMM, then K + V^T GEMMs in one launch
  {
    dim3 g(DIMN/128, ROWS/128);
    k_gemm_q<<<g,256,0,stream>>>(xhi, xlo, wqT, qhib, qlob, DIMN, DIMN);
  }
  {
    dim3 g(KVD/128, ROWS/128, 2);
    k_gemm_kvt<<<g,256,0,stream>>>(xhi, xlo, wkT, wvT, khib, klob, vTb, DIMN);
  }

  // 4) attention (balanced pairing, barrier-free)
  {
    dim3 g(NT/2, NH, BATCH);
    k_attn<<<g,256,0,stream>>>(qhib, qlob, khib, klob, vTb, atto);
  }

  // 5) output GEMM -> f32
  {
    dim3 g(DIMN/128, ROWS/128);
    k_gemm_o<<<g,256,0,stream>>>(atto, woT, out, DIMN, DIMN);
  }
}

// Round 7
// 490.743 us; speedup vs baseline: 1.8953x; 1.4028x over previous
//
#include <hip/hip_runtime.h>
#include <hip/hip_bf16.h>
#include <stdint.h>

#define DIMN 2048
#define KVD  512
#define NH   32
#define BATCH 2
#define SEQ  2048
#define ROWS (BATCH*SEQ)   // 4096
#define NT   (SEQ/64)      // 32 k/q tiles of 64

typedef __attribute__((ext_vector_type(4))) float f32x4;
typedef __attribute__((ext_vector_type(8))) short bf16x8;

__device__ __forceinline__ float bf2f(short s){
  union{uint32_t u;float f;} v; v.u=((uint32_t)(uint16_t)s)<<16; return v.f;
}
__device__ __forceinline__ short f2bf(float f){
  union{float f;uint32_t u;} v; v.f=f;
  uint32_t r=(v.u + 0x7fffu + ((v.u>>16)&1u))>>16; return (short)r;
}
__device__ __forceinline__ f32x4 mfma16(bf16x8 a, bf16x8 b, f32x4 c){
  return __builtin_amdgcn_mfma_f32_16x16x32_bf16(a,b,c,0,0,0);
}
__device__ __forceinline__ short ternbf(float v, float thr){
  return v > thr ? (short)0x3F80 : (v < -thr ? (short)0xBF80 : (short)0);
}

// ---------------- abs-mean reduction (deterministic, two stage) ----------------
__global__ void k_abssum4(const float* __restrict__ w0, const float* __restrict__ w1,
                          const float* __restrict__ w2, const float* __restrict__ w3,
                          float* __restrict__ partial){
  __shared__ float red[256];
  const float* ptrs[4] = {w0, w1, w2, w3};
  const int ns[4] = {DIMN*DIMN, KVD*DIMN, KVD*DIMN, DIMN*DIMN};
  const int wi = blockIdx.y;
  const float* w = ptrs[wi];
  const int n = ns[wi];
  float s = 0.f;
  for (int i = blockIdx.x*256 + threadIdx.x; i < n; i += 256*gridDim.x) s += fabsf(w[i]);
  red[threadIdx.x] = s; __syncthreads();
  for (int o = 128; o > 0; o >>= 1){
    if (threadIdx.x < o) red[threadIdx.x] += red[threadIdx.x+o];
    __syncthreads();
  }
  if (threadIdx.x == 0) partial[wi*256 + blockIdx.x] = red[0];
}

__global__ void k_scales(const float* __restrict__ partial, float* __restrict__ scales){
  __shared__ float red[256];
  int t = threadIdx.x;
  const int counts[4] = {DIMN*DIMN, KVD*DIMN, KVD*DIMN, DIMN*DIMN};
  for (int wi = 0; wi < 4; wi++){
    red[t] = partial[wi*256 + t]; __syncthreads();
    for (int o = 128; o > 0; o >>= 1){
      if (t < o) red[t] += red[t+o];
      __syncthreads();
    }
    if (t == 0){
      float mean = red[0] / (float)counts[wi];
      scales[wi] = 0.05f * fmaxf(mean, 1e-6f);
    }
    __syncthreads();
  }
}

// ---------------- pre-pass: x -> hi/lo bf16 ----------------
__global__ void k_prep_x(const float* __restrict__ x, short* __restrict__ hi,
                         short* __restrict__ lo){
  long i = ((long)blockIdx.x*256 + threadIdx.x)*8;
  f32x4 a = *(const f32x4*)(x+i);
  f32x4 b = *(const f32x4*)(x+i+4);
  bf16x8 h, l;
  #pragma unroll
  for (int j = 0; j < 4; j++){
    short p = f2bf(a[j]); h[j]   = p; l[j]   = f2bf(a[j]-bf2f(p));
    short q = f2bf(b[j]); h[4+j] = q; l[4+j] = f2bf(b[j]-bf2f(q));
  }
  *(bf16x8*)(hi+i) = h;
  *(bf16x8*)(lo+i) = l;
}

// ---------------- pre-pass: ternarize all 4 weights -> bf16 ----------------
__global__ void k_tern4(const float* __restrict__ w0, const float* __restrict__ w1,
                        const float* __restrict__ w2, const float* __restrict__ w3,
                        short* __restrict__ o0, short* __restrict__ o1,
                        short* __restrict__ o2, short* __restrict__ o3,
                        const float* __restrict__ scales){
  const float* ws[4] = {w0, w1, w2, w3};
  short* os[4] = {o0, o1, o2, o3};
  const int ns[4] = {DIMN*DIMN, KVD*DIMN, KVD*DIMN, DIMN*DIMN};
  const int wi = blockIdx.y;
  long i = ((long)blockIdx.x*256 + threadIdx.x)*8;
  if (i >= ns[wi]) return;
  const float thr = scales[wi];
  const float* w = ws[wi];
  f32x4 a = *(const f32x4*)(w+i);
  f32x4 b = *(const f32x4*)(w+i+4);
  bf16x8 t;
  #pragma unroll
  for (int j = 0; j < 4; j++){
    t[j]   = ternbf(a[j], thr);
    t[4+j] = ternbf(b[j], thr);
  }
  *(bf16x8*)(os[wi]+i) = t;
}

// ---------------- GEMM core (bf16 inputs, BK=64, 128x128 tile) ----------------
template<int SPLITA, int SPLITB, int OUTF32>
__device__ __forceinline__ void gemm_core(
    const short* __restrict__ Ahg, const short* __restrict__ Alg,
    const short* __restrict__ Bg,  const short* __restrict__ Blg,
    float* __restrict__ Of, short* __restrict__ Oh, short* __restrict__ Ol,
    bool writelo, int N, int K, int bn, int bm,
    short (*AhS)[72], short (*AlS)[72], short (*BsS)[72], short (*BlS)[72]){
  const int tid = threadIdx.x, lane = tid & 63, w = tid >> 6;
  const int wr = w >> 1, wc = w & 1;
  const int la = lane & 15, kg = lane >> 4;
  const int srow = tid >> 1, sc = (tid & 1) * 32;
  f32x4 acc[4][4] = {};
  for (int k0 = 0; k0 < K; k0 += 64){
    {
      const short* ap = Ahg + (long)(bm+srow)*K + k0 + sc;
      #pragma unroll
      for (int i = 0; i < 4; i++)
        *(bf16x8*)&AhS[srow][sc+i*8] = *(const bf16x8*)(ap + i*8);
    }
    if constexpr (SPLITA){
      const short* alp = Alg + (long)(bm+srow)*K + k0 + sc;
      #pragma unroll
      for (int i = 0; i < 4; i++)
        *(bf16x8*)&AlS[srow][sc+i*8] = *(const bf16x8*)(alp + i*8);
    }
    {
      const short* bp = Bg + (long)(bn+srow)*K + k0 + sc;
      #pragma unroll
      for (int i = 0; i < 4; i++)
        *(bf16x8*)&BsS[srow][sc+i*8] = *(const bf16x8*)(bp + i*8);
    }
    if constexpr (SPLITB){
      const short* blp = Blg + (long)(bn+srow)*K + k0 + sc;
      #pragma unroll
      for (int i = 0; i < 4; i++)
        *(bf16x8*)&BlS[srow][sc+i*8] = *(const bf16x8*)(blp + i*8);
    }
    __syncthreads();
    #pragma unroll
    for (int ks = 0; ks < 2; ks++){
      bf16x8 af[4], bfr[4];
      #pragma unroll
      for (int mi = 0; mi < 4; mi++)
        af[mi] = *(bf16x8*)&AhS[wr*64 + mi*16 + la][ks*32 + kg*8];
      #pragma unroll
      for (int ni = 0; ni < 4; ni++)
        bfr[ni] = *(bf16x8*)&BsS[wc*64 + ni*16 + la][ks*32 + kg*8];
      #pragma unroll
      for (int mi = 0; mi < 4; mi++)
        #pragma unroll
        for (int ni = 0; ni < 4; ni++)
          acc[mi][ni] = mfma16(af[mi], bfr[ni], acc[mi][ni]);
      if constexpr (SPLITA){
        bf16x8 alf[4];
        #pragma unroll
        for (int mi = 0; mi < 4; mi++)
          alf[mi] = *(bf16x8*)&AlS[wr*64 + mi*16 + la][ks*32 + kg*8];
        #pragma unroll
        for (int mi = 0; mi < 4; mi++)
          #pragma unroll
          for (int ni = 0; ni < 4; ni++)
            acc[mi][ni] = mfma16(alf[mi], bfr[ni], acc[mi][ni]);
      }
      if constexpr (SPLITB){
        bf16x8 blf[4];
        #pragma unroll
        for (int ni = 0; ni < 4; ni++)
          blf[ni] = *(bf16x8*)&BlS[wc*64 + ni*16 + la][ks*32 + kg*8];
        #pragma unroll
        for (int mi = 0; mi < 4; mi++)
          #pragma unroll
          for (int ni = 0; ni < 4; ni++)
            acc[mi][ni] = mfma16(af[mi], blf[ni], acc[mi][ni]);
      }
    }
    __syncthreads();
  }
  #pragma unroll
  for (int mi = 0; mi < 4; mi++)
    #pragma unroll
    for (int ni = 0; ni < 4; ni++)
      #pragma unroll
      for (int rr = 0; rr < 4; rr++){
        long row = bm + wr*64 + mi*16 + kg*4 + rr;
        long col = bn + wc*64 + ni*16 + la;
        float v = acc[mi][ni][rr];
        if constexpr (OUTF32){
          Of[row*(long)N + col] = v;
        } else {
          short hb = f2bf(v);
          Oh[row*(long)N + col] = hb;
          if (writelo)
            Ol[row*(long)N + col] = f2bf(v - bf2f(hb));
        }
      }
}

__global__ __launch_bounds__(256) void k_gemm_q(
    const short* __restrict__ Ahg, const short* __restrict__ Alg,
    const short* __restrict__ Bg, short* __restrict__ Oh, short* __restrict__ Ol,
    int N, int K){
  __shared__ short S0[128][72];
  __shared__ short S1[128][72];
  __shared__ short S2[128][72];
  gemm_core<1,0,0>(Ahg, Alg, Bg, nullptr, nullptr, Oh, Ol, true, N, K,
                   blockIdx.x*128, blockIdx.y*128, S0, S1, S2, nullptr);
}

// z=0: K GEMM  khi/klo[token][d] = (xhi+xlo) wkT^T
// z=1: V^T GEMM  vT[d][token] = wvT (xhi+xlo)^T  (roles swapped)
__global__ __launch_bounds__(256) void k_gemm_kvt(
    const short* __restrict__ xhi, const short* __restrict__ xlo,
    const short* __restrict__ wkT, const short* __restrict__ wvT,
    short* __restrict__ KOh, short* __restrict__ KOl, short* __restrict__ VT,
    int K){
  __shared__ short S0[128][72];
  __shared__ short S1[128][72];
  __shared__ short S2[128][72];
  if (blockIdx.z == 0){
    gemm_core<1,0,0>(xhi, xlo, wkT, nullptr, nullptr, KOh, KOl, true, KVD, K,
                     blockIdx.x*128, blockIdx.y*128, S0, S1, S2, nullptr);
  } else {
    gemm_core<0,1,0>(wvT, nullptr, xhi, xlo, nullptr, VT, nullptr, false, ROWS, K,
                     blockIdx.y*128, blockIdx.x*128, S0, nullptr, S1, S2);
  }
}

__global__ __launch_bounds__(256) void k_gemm_o(
    const short* __restrict__ Ahg, const short* __restrict__ Bg,
    float* __restrict__ Of, int N, int K){
  __shared__ short S0[128][72];
  __shared__ short S2[128][72];
  gemm_core<0,0,1>(Ahg, nullptr, Bg, nullptr, Of, nullptr, nullptr, false, N, K,
                   blockIdx.x*128, blockIdx.y*128, S0, nullptr, S2, nullptr);
}

// ---------------- GQA causal flash attention ----------------
// Balanced pairing: grid (NT/2=16, head=32, batch=2); block qp does q-tiles {qp, NT-1-qp}
// = exactly 33 k-tiles (uniform). 4 waves x 16 q-rows.
// K-hi/K-lo/V^T tiles cooperatively staged in LDS (coalesced 32B/thread copies;
// V^T precomputed by k_gemm_kvt so no transpose scatter). Pad-72 rows.
// Scores use 3-MFMA hi/lo split for fp32-class accuracy.
__global__ __launch_bounds__(256) void k_attn(
    const short* __restrict__ qhi, const short* __restrict__ qlo,
    const short* __restrict__ khi, const short* __restrict__ klo,
    const short* __restrict__ vT, short* __restrict__ attout){
  __shared__ short Kh[64][72];
  __shared__ short Kl[64][72];
  __shared__ short Vt[64][72];
  __shared__ short P[64][72];
  const int qp = blockIdx.x, h = blockIdx.y, b = blockIdx.z;
  const int g = h >> 2;
  const int tid = threadIdx.x, w = tid >> 6, lane = tid & 63;
  const int la = lane & 15, kg = lane >> 4;
  const int trow = tid >> 2, tcol = (tid & 3) * 16;   // staging coords

  for (int phase = 0; phase < 2; phase++){
    const int qt = phase ? (NT - 1 - qp) : qp;
    const int qbase = qt*64;

    bf16x8 qh[2], ql[2];
    {
      long qrow = (long)(b*SEQ + qbase + w*16 + la);
      #pragma unroll
      for (int ks = 0; ks < 2; ks++){
        long off = qrow*DIMN + h*64 + ks*32 + kg*8;
        qh[ks] = *(const bf16x8*)(qhi + off);
        ql[ks] = *(const bf16x8*)(qlo + off);
      }
    }
    f32x4 Oacc[4] = {};
    float m[4], l[4];
    #pragma unroll
    for (int r = 0; r < 4; r++){ m[r] = -INFINITY; l[r] = 0.f; }

    for (int kt = 0; kt <= qt; kt++){
      // ---- cooperative stage: K-hi, K-lo (row=token), V^T (row=d) ----
      __syncthreads();   // protect previous tile's reads
      {
        const short* ksrc  = khi + (long)(b*SEQ + kt*64 + trow)*KVD + g*64 + tcol;
        const short* klsrc = klo + (long)(b*SEQ + kt*64 + trow)*KVD + g*64 + tcol;
        const short* vsrc  = vT  + (long)(g*64 + trow)*ROWS + b*SEQ + kt*64 + tcol;
        *(bf16x8*)&Kh[trow][tcol]   = *(const bf16x8*)ksrc;
        *(bf16x8*)&Kh[trow][tcol+8] = *(const bf16x8*)(ksrc + 8);
        *(bf16x8*)&Kl[trow][tcol]   = *(const bf16x8*)klsrc;
        *(bf16x8*)&Kl[trow][tcol+8] = *(const bf16x8*)(klsrc + 8);
        *(bf16x8*)&Vt[trow][tcol]   = *(const bf16x8*)vsrc;
        *(bf16x8*)&Vt[trow][tcol+8] = *(const bf16x8*)(vsrc + 8);
      }
      __syncthreads();

      // ---- scores (3-MFMA split) ----
      f32x4 s[4];
      __builtin_amdgcn_s_setprio(1);
      #pragma unroll
      for (int ni = 0; ni < 4; ni++){
        f32x4 a = {0.f,0.f,0.f,0.f};
        #pragma unroll
        for (int ks = 0; ks < 2; ks++){
          bf16x8 kh = *(bf16x8*)&Kh[ni*16 + la][ks*32 + kg*8];
          bf16x8 kl = *(bf16x8*)&Kl[ni*16 + la][ks*32 + kg*8];
          a = mfma16(qh[ks], kh, a);
          a = mfma16(ql[ks], kh, a);
          a = mfma16(qh[ks], kl, a);
        }
        s[ni] = a;
      }
      __builtin_amdgcn_s_setprio(0);

      const bool lastTile = (kt == qt);
      #pragma unroll
      for (int ni = 0; ni < 4; ni++)
        #pragma unroll
        for (int r = 0; r < 4; r++){
          float v = s[ni][r] * 0.125f;
          if (lastTile){
            int kc = kt*64 + ni*16 + la;
            int qr = qbase + w*16 + kg*4 + r;
            if (kc > qr) v = -INFINITY;
          }
          s[ni][r] = v;
        }

      // ---- online softmax (16-lane row groups) ----
      float ef[4];
      #pragma unroll
      for (int r = 0; r < 4; r++){
        float v = fmaxf(fmaxf(s[0][r], s[1][r]), fmaxf(s[2][r], s[3][r]));
        for (int o = 1; o < 16; o <<= 1) v = fmaxf(v, __shfl_xor(v, o, 64));
        float mn = fmaxf(m[r], v);
        ef[r] = __expf(m[r] - mn);
        m[r] = mn;
      }
      #pragma unroll
      for (int r = 0; r < 4; r++){
        float rs = 0.f;
        #pragma unroll
        for (int ni = 0; ni < 4; ni++){
          float p = __expf(s[ni][r] - m[r]);
          s[ni][r] = p;
          rs += p;
        }
        for (int o = 1; o < 16; o <<= 1) rs += __shfl_xor(rs, o, 64);
        l[r] = l[r]*ef[r] + rs;
      }
      #pragma unroll
      for (int d = 0; d < 4; d++)
        #pragma unroll
        for (int r = 0; r < 4; r++) Oacc[d][r] *= ef[r];

      // ---- P -> LDS bf16 (wave-private rows), PV from LDS ----
      #pragma unroll
      for (int ni = 0; ni < 4; ni++)
        #pragma unroll
        for (int r = 0; r < 4; r++)
          P[w*16 + kg*4 + r][ni*16 + la] = f2bf(s[ni][r]);

      __builtin_amdgcn_s_setprio(1);
      #pragma unroll
      for (int ks = 0; ks < 2; ks++){
        bf16x8 pa = *(bf16x8*)&P[w*16 + la][ks*32 + kg*8];
        #pragma unroll
        for (int d = 0; d < 4; d++){
          bf16x8 vb = *(bf16x8*)&Vt[d*16 + la][ks*32 + kg*8];
          Oacc[d] = mfma16(pa, vb, Oacc[d]);
        }
      }
      __builtin_amdgcn_s_setprio(0);
    }

    // ---- finalize ----
    #pragma unroll
    for (int d = 0; d < 4; d++)
      #pragma unroll
      for (int r = 0; r < 4; r++){
        float v = Oacc[d][r] / l[r];
        long row = (long)(b*SEQ + qbase + w*16 + kg*4 + r);
        attout[row*DIMN + h*64 + d*16 + la] = f2bf(v);
      }
    __syncthreads();   // P/K/V reuse across phases
  }
}

// ---------------- host ----------------
extern "C" void kernel_launch(void* const* d_in, const int* in_sizes, int n_in,
                              void* d_out, int out_size, void* d_ws, size_t ws_size,
                              hipStream_t stream){
  const float* x  = (const float*)d_in[0];
  const float* wq = (const float*)d_in[1];
  const float* wk = (const float*)d_in[2];
  const float* wv = (const float*)d_in[3];
  const float* wo = (const float*)d_in[4];
  float* out = (float*)d_out;
  char* ws = (char*)d_ws;

  const size_t SZ_QD = (size_t)ROWS*DIMN*2;   // 16 MB
  const size_t SZ_KD = (size_t)ROWS*KVD*2;    // 4 MB
  const size_t SZ_WQ = (size_t)DIMN*DIMN*2;   // 8 MB
  const size_t SZ_WK = (size_t)KVD*DIMN*2;    // 2 MB
  const size_t NEED = 65536 + 2*SZ_QD + 2*SZ_WQ + 2*SZ_WK + 2*SZ_QD + 3*SZ_KD;
  if (ws_size < NEED) return;

  float* scales   = (float*)ws;
  float* partials = (float*)(ws + 1024);
  size_t off = 65536;
  auto alloc = [&](size_t bytes)->char*{
    char* p = ws + off; off += (bytes + 255) & ~(size_t)255; return p;
  };
  short* xhi = (short*)alloc(SZ_QD);
  short* xlo = (short*)alloc(SZ_QD);
  short* wqT = (short*)alloc(SZ_WQ);
  short* wkT = (short*)alloc(SZ_WK);
  short* wvT = (short*)alloc(SZ_WK);
  short* woT = (short*)alloc(SZ_WQ);
  short* qhib = (short*)alloc(SZ_QD);
  short* qlob = (short*)alloc(SZ_QD);
  short* khib = (short*)alloc(SZ_KD);
  short* klob = (short*)alloc(SZ_KD);
  short* vTb  = (short*)alloc(SZ_KD);   // V^T: [KVD][ROWS]
  short* atto = xhi;                    // alias: xhi dead after KVT GEMM

  // 1) thresholds
  {
    dim3 g(256, 4);
    k_abssum4<<<g,256,0,stream>>>(wq, wk, wv, wo, partials);
  }
  k_scales<<<1,256,0,stream>>>(partials, scales);

  // 2) pre-convert operands
  {
    dim3 g(2048, 4);
    k_tern4<<<g,256,0,stream>>>(wq, wk, wv, wo, wqT, wkT, wvT, woT, scales);
  }
  k_prep_x<<<4096,256,0,stream>>>(x, xhi, xlo);

  // 3) Q GEMM, then K + V^T GEMMs in one launch
  {
    dim3 g(DIMN/128, ROWS/128);
    k_gemm_q<<<g,256,0,stream>>>(xhi, xlo, wqT, qhib, qlob, DIMN, DIMN);
  }
  {
    dim3 g(KVD/128, ROWS/128, 2);
    k_gemm_kvt<<<g,256,0,stream>>>(xhi, xlo, wkT, wvT, khib, klob, vTb, DIMN);
  }

  // 4) attention (balanced pairing, LDS-staged K/V)
  {
    dim3 g(NT/2, NH, BATCH);
    k_attn<<<g,256,0,stream>>>(qhib, qlob, khib, klob, vTb, atto);
  }

  // 5) output GEMM -> f32
  {
    dim3 g(DIMN/128, ROWS/128);
    k_gemm_o<<<g,256,0,stream>>>(atto, woT, out, DIMN, DIMN);
  }
}